// Round 9
// baseline (439.992 us; speedup 1.0000x reference)
//
#include <hip/hip_runtime.h>

#define DD 128
#define CHUNK 2048      // edges per pass-1 block
#define BSH 7           // bucket = dst >> 7  (128 nodes/bucket)
#define MAXBK 1024      // max coarse buckets (N <= 131072)

typedef _Float16 half8 __attribute__((ext_vector_type(8)));
typedef _Float16 half4v __attribute__((ext_vector_type(4)));
typedef float floatx4 __attribute__((ext_vector_type(4)));

// ---------------- bucket-level histogram (LDS-aggregated) ----------------
__global__ __launch_bounds__(256) void k_bhist(const int* __restrict__ dst,
                                               int* __restrict__ bcounts, int E, int NB) {
    __shared__ int lh[MAXBK];
    int tid = threadIdx.x;
    for (int b = tid; b < MAXBK; b += 256) lh[b] = 0;
    __syncthreads();
    int stride = gridDim.x * 256;
    for (int k = blockIdx.x * 256 + tid; k < E; k += stride)
        atomicAdd(&lh[dst[k] >> BSH], 1);
    __syncthreads();
    for (int b = tid; b < NB; b += 256) {
        int c = lh[b];
        if (c) atomicAdd(&bcounts[b], c);
    }
}

// ---------------- bucket scan: bucket_start, row_start[N], zero gcur ----------------
__global__ __launch_bounds__(1024) void k_bscan(const int* __restrict__ bcounts,
                                                int* __restrict__ bucket_start,
                                                int* __restrict__ gcur,
                                                int* __restrict__ row_start_N,
                                                int NB, int E) {
    __shared__ int s[1024];
    int t = threadIdx.x;
    int v = (t < NB) ? bcounts[t] : 0;
    s[t] = v;
    __syncthreads();
    for (int off = 1; off < 1024; off <<= 1) {
        int x = (t >= off) ? s[t - off] : 0;
        __syncthreads();
        s[t] += x;
        __syncthreads();
    }
    if (t < NB) bucket_start[t] = s[t] - v;           // exclusive
    if (t == NB - 1) bucket_start[NB] = s[t];         // == E
    if (t == 0) *row_start_N = E;
    gcur[t] = 0;
}

// ---------------- pass 1: bucket-bin edges, direct global run-writes ----------------
// rec = { src | dlocal<<17 , w_bits }   (requires N <= 2^17, dlocal < 128)
__global__ __launch_bounds__(256) void k_pass1(const int* __restrict__ src,
                                               const int* __restrict__ dst,
                                               const float* __restrict__ w,
                                               const int* __restrict__ bucket_start,
                                               int* __restrict__ gcur,
                                               int2* __restrict__ out, int E, int NB) {
    __shared__ int lhist[MAXBK];
    __shared__ int lbase[MAXBK];
    __shared__ int lcur[MAXBK];
    int tid = threadIdx.x;
    int beg = blockIdx.x * CHUNK;
    int end = min(beg + CHUNK, E);

    for (int b = tid; b < MAXBK; b += 256) { lhist[b] = 0; lcur[b] = 0; }
    __syncthreads();
    for (int k = beg + tid; k < end; k += 256)
        atomicAdd(&lhist[dst[k] >> BSH], 1);
    __syncthreads();
    for (int b = tid; b < NB; b += 256) {
        int c = lhist[b];
        if (c) lbase[b] = bucket_start[b] + atomicAdd(&gcur[b], c);
    }
    __syncthreads();
    for (int k = beg + tid; k < end; k += 256) {
        int d = dst[k];
        int b = d >> BSH;
        int loc = atomicAdd(&lcur[b], 1);
        out[lbase[b] + loc] =
            make_int2(src[k] | ((d & ((1 << BSH) - 1)) << 17), __float_as_int(w[k]));
    }
}

// ---------------- pass 2: per-bucket count+scan+place, all LDS-local ----------------
__global__ __launch_bounds__(512) void k_pass2(const int2* __restrict__ bkt,
                                               const int* __restrict__ bucket_start,
                                               int* __restrict__ row_start,
                                               int2* __restrict__ edges, int N) {
    __shared__ int lhist[1 << BSH];
    __shared__ int loff[1 << BSH];
    __shared__ int lcur[1 << BSH];
    int tid = threadIdx.x;
    int b = blockIdx.x;
    int d0 = b << BSH;
    int sb = bucket_start[b], se = bucket_start[b + 1];

    if (tid < (1 << BSH)) lhist[tid] = 0;
    __syncthreads();
    for (int i = sb + tid; i < se; i += 512)
        atomicAdd(&lhist[(unsigned)bkt[i].x >> 17], 1);
    __syncthreads();
    if (tid < 64) {
        int base = tid * 2, v[2], s = 0;
        #pragma unroll
        for (int j = 0; j < 2; ++j) { v[j] = lhist[base + j]; s += v[j]; }
        int sc = s;
        #pragma unroll
        for (int off = 1; off < 64; off <<= 1) {
            int t = __shfl_up(sc, off, 64);
            if (tid >= off) sc += t;
        }
        int excl = sc - s;
        #pragma unroll
        for (int j = 0; j < 2; ++j) {
            loff[base + j] = excl; lcur[base + j] = excl; excl += v[j];
        }
    }
    __syncthreads();
    if (tid < (1 << BSH)) {
        int d = d0 + tid;
        if (d < N) row_start[d] = sb + loff[tid];
    }
    for (int i = sb + tid; i < se; i += 512) {
        int2 r = bkt[i];
        int dl = (unsigned)r.x >> 17;
        int p = sb + atomicAdd(&lcur[dl], 1);
        edges[p] = make_int2(r.x & 0x1FFFF, r.y);
    }
}

// ---------------- casts ----------------
__global__ void k_cast_f2h(const float* __restrict__ in, _Float16* __restrict__ out, int n4) {
    int i = blockIdx.x * blockDim.x + threadIdx.x;
    if (i >= n4) return;
    float4 v = reinterpret_cast<const float4*>(in)[i];
    half4v h;
    h.x = (_Float16)v.x; h.y = (_Float16)v.y; h.z = (_Float16)v.z; h.w = (_Float16)v.w;
    reinterpret_cast<half4v*>(out)[i] = h;
}

__global__ void k_cast_wT(const float* __restrict__ W, _Float16* __restrict__ Wt) {
    int idx = blockIdx.x * blockDim.x + threadIdx.x;
    int n = idx >> 7, k = idx & 127;
    Wt[n * DD + k] = (_Float16)W[k * DD + n];
}

// ---------------- fused aggregate + MFMA GEMM ----------------
// Block = 64 nodes, wave = 16 nodes.
// Phase 1: 4 rounds x 4 concurrent nodes; group g (16 lanes, 8 cols/lane) owns
//          node base+r*4+g; masked tail (wv=0) instead of wasted remainder.
// __syncthreads() between phases: cross-lane LDS write->read handoff needs the
// lgkmcnt-drain + barrier (R8's barrier-free version read stale LDS -> zeros).
// Phase 2: LDS rows -> A-frags (ds_read_b128), operand-swapped MFMA
//          (D col = A-row, D row = W-col), contiguous float4/half4 epilogue.
__global__ __launch_bounds__(256) void k_agg_gemm(const _Float16* __restrict__ x,
                                                  const int* __restrict__ row_start,
                                                  const int2* __restrict__ edges,
                                                  const _Float16* __restrict__ Wt,
                                                  const float* __restrict__ bias,
                                                  const _Float16* __restrict__ resid_h,
                                                  float* __restrict__ out_f32,
                                                  _Float16* __restrict__ out_f16,
                                                  int N) {
    __shared__ __align__(16) _Float16 rows[4][16][136];   // 272 B row stride
    int wave = threadIdx.x >> 6;
    int lane = threadIdx.x & 63;
    int g = lane >> 4;      // group / quad
    int sl = lane & 15;
    int base = blockIdx.x * 64 + wave * 16;

    // ---- phase 1: aggregate 16 rows ----
    #pragma unroll
    for (int r = 0; r < 4; ++r) {
        int lr = r * 4 + g;
        int n = base + lr;
        float acc[8] = {0.f, 0.f, 0.f, 0.f, 0.f, 0.f, 0.f, 0.f};
        int beg = 0, end = 0;
        if (n < N) { beg = row_start[n]; end = row_start[n + 1]; }
        int iters = (end - beg + 3) >> 2;
        int it1 = max(iters, __shfl_xor(iters, 16, 64));
        int itm = max(it1, __shfl_xor(it1, 32, 64));      // max over 4 groups
        int clampHi = max(end - 1, 0);
        for (int t = 0; t < itm; ++t) {
            int e0 = beg + t * 4;
            int2 e[4];
            #pragma unroll
            for (int u = 0; u < 4; ++u)
                e[u] = edges[min(e0 + u, clampHi)];
            half8 v[4];
            #pragma unroll
            for (int u = 0; u < 4; ++u)
                v[u] = *reinterpret_cast<const half8*>(x + (size_t)e[u].x * DD + sl * 8);
            #pragma unroll
            for (int u = 0; u < 4; ++u) {
                float wv = (e0 + u < end) ? __int_as_float(e[u].y) : 0.f;
                #pragma unroll
                for (int j = 0; j < 8; ++j)
                    acc[j] = fmaf((float)v[u][j], wv, acc[j]);
            }
        }
        half8 o;
        #pragma unroll
        for (int j = 0; j < 8; ++j) o[j] = (_Float16)acc[j];
        *reinterpret_cast<half8*>(&rows[wave][lr][sl * 8]) = o;
    }

    __syncthreads();   // make phase-1 LDS writes visible to phase-2 reads

    // ---- phase 2: GEMM of this wave's 16 rows ----
    int m = sl;           // A-row within tile == D col
    int q = g;            // k-chunk quad == D row block
    floatx4 acc2[8];
    #pragma unroll
    for (int c = 0; c < 8; ++c) acc2[c] = (floatx4){0.f, 0.f, 0.f, 0.f};

    #pragma unroll
    for (int ks = 0; ks < 4; ++ks) {
        int kbase = ks * 32 + q * 8;
        half8 a = *reinterpret_cast<const half8*>(&rows[wave][m][kbase]);
        #pragma unroll
        for (int c = 0; c < 8; ++c) {
            half8 b = *reinterpret_cast<const half8*>(Wt + (size_t)(c * 16 + m) * DD + kbase);
            acc2[c] = __builtin_amdgcn_mfma_f32_16x16x32_f16(b, a, acc2[c], 0, 0, 0);
        }
    }

    int row = base + m;
    if (row < N) {
        size_t rb = (size_t)row * DD;
        #pragma unroll
        for (int c = 0; c < 8; ++c) {
            int col = c * 16 + q * 4;
            float4 bv = *reinterpret_cast<const float4*>(&bias[col]);
            float o[4] = {acc2[c][0] + bv.x, acc2[c][1] + bv.y,
                          acc2[c][2] + bv.z, acc2[c][3] + bv.w};
            #pragma unroll
            for (int r = 0; r < 4; ++r) o[r] = o[r] > 0.f ? o[r] : 0.f;
            if (resid_h) {
                half4v r4 = *reinterpret_cast<const half4v*>(&resid_h[rb + col]);
                #pragma unroll
                for (int r = 0; r < 4; ++r) o[r] += (float)r4[r];
            }
            if (out_f32)
                *reinterpret_cast<float4*>(&out_f32[rb + col]) =
                    make_float4(o[0], o[1], o[2], o[3]);
            if (out_f16) {
                half4v h;
                #pragma unroll
                for (int r = 0; r < 4; ++r) h[r] = (_Float16)o[r];
                *reinterpret_cast<half4v*>(&out_f16[rb + col]) = h;
            }
        }
    }
}

// ---------------- per-subgraph mean pool + target residual ----------------
__global__ __launch_bounds__(128) void k_pool(const float* __restrict__ h,
                                              const int* __restrict__ target,
                                              const float* __restrict__ size_subg,
                                              float* __restrict__ pooled, int SZ) {
    int b = blockIdx.x;
    int d = threadIdx.x;
    const float* hp = h + (size_t)b * SZ * DD;
    float s = 0.f;
    for (int n = 0; n < SZ; ++n) s += hp[(size_t)n * DD + d];
    int t = target[b];
    float p = s / size_subg[b] + h[(size_t)t * DD + d];
    pooled[b * DD + d] = p;
}

// ---------------- final: relu(pooled @ Wp + bp), L2-normalize rows ----------------
__global__ __launch_bounds__(128) void k_final(const float* __restrict__ pooled,
                                               const float* __restrict__ Wp,
                                               const float* __restrict__ bp,
                                               float* __restrict__ out) {
    __shared__ float p[DD];
    __shared__ float wsum[2];
    int b = blockIdx.x;
    int c = threadIdx.x;
    p[c] = pooled[b * DD + c];
    __syncthreads();
    float acc = 0.f;
    #pragma unroll 4
    for (int k = 0; k < DD; ++k) acc = fmaf(p[k], Wp[k * DD + c], acc);
    float e = acc + bp[c];
    e = e > 0.f ? e : 0.f;
    float sq = e * e;
    #pragma unroll
    for (int off = 32; off > 0; off >>= 1) sq += __shfl_down(sq, off, 64);
    int lane = c & 63, w = c >> 6;
    if (lane == 0) wsum[w] = sq;
    __syncthreads();
    float norm = sqrtf(wsum[0] + wsum[1]);
    float scale = 1.f / fmaxf(norm, 1e-12f);
    out[b * DD + c] = e * scale;
}

extern "C" void kernel_launch(void* const* d_in, const int* in_sizes, int n_in,
                              void* d_out, int out_size, void* d_ws, size_t ws_size,
                              hipStream_t stream) {
    const float* feat      = (const float*)d_in[0];
    const float* edge_w    = (const float*)d_in[1];
    const float* W1        = (const float*)d_in[2];
    const float* b1        = (const float*)d_in[3];
    const float* W2        = (const float*)d_in[4];
    const float* b2        = (const float*)d_in[5];
    const float* Wp        = (const float*)d_in[6];
    const float* bp        = (const float*)d_in[7];
    const float* size_subg = (const float*)d_in[8];
    const int*   edge_src  = (const int*)d_in[9];
    const int*   edge_dst  = (const int*)d_in[10];
    const int*   target    = (const int*)d_in[12];

    const int N  = in_sizes[0] / DD;
    const int E  = in_sizes[1];
    const int B  = in_sizes[8];
    const int SZ = N / B;

    const int NB = (N + (1 << BSH) - 1) >> BSH;   // coarse buckets (<= MAXBK)

    char* ws = (char*)d_ws;
    size_t off = 0;
    auto alloc = [&](size_t bytes) {
        void* p = ws + off;
        off += (bytes + 255) & ~(size_t)255;
        return p;
    };
    // region0: feat_h (first half); later overlaid by fp32 H (feat_h dead by then)
    char* region0   = (char*)alloc((size_t)N * DD * 4 + 1024);
    _Float16* feat_h = (_Float16*)region0;
    float*    H      = (float*)region0;
    _Float16* h1_h   = (_Float16*)alloc((size_t)N * DD * 2);
    _Float16* W1t    = (_Float16*)alloc((size_t)DD * DD * 2);
    _Float16* W2t    = (_Float16*)alloc((size_t)DD * DD * 2);
    int*   row_start = (int*)alloc(((size_t)N + 1) * 4);
    int*   bcounts      = (int*)alloc((size_t)MAXBK * 4);
    int*   bucket_start = (int*)alloc(((size_t)MAXBK + 1) * 4);
    int*   gcur         = (int*)alloc((size_t)MAXBK * 4);
    int2*  edges_bkt = (int2*)alloc((size_t)E * 8);
    int2*  edges     = (int2*)alloc((size_t)E * 8);
    float* pooled    = (float*)alloc((size_t)B * DD * 4);

    // ---- CSR build: bucket hist -> bucket scan -> pass1 -> pass2 ----
    hipMemsetAsync(bcounts, 0, (size_t)MAXBK * 4, stream);
    k_bhist<<<256, 256, 0, stream>>>(edge_dst, bcounts, E, NB);
    k_bscan<<<1, 1024, 0, stream>>>(bcounts, bucket_start, gcur, row_start + N, NB, E);
    int p1Blocks = (E + CHUNK - 1) / CHUNK;
    k_pass1<<<p1Blocks, 256, 0, stream>>>(edge_src, edge_dst, edge_w, bucket_start,
                                          gcur, edges_bkt, E, NB);
    k_pass2<<<NB, 512, 0, stream>>>(edges_bkt, bucket_start, row_start, edges, N);

    // ---- casts ----
    int n4 = N * DD / 4;
    k_cast_f2h<<<(n4 + 255) / 256, 256, 0, stream>>>(feat, feat_h, n4);
    k_cast_wT<<<64, 256, 0, stream>>>(W1, W1t);
    k_cast_wT<<<64, 256, 0, stream>>>(W2, W2t);

    int fusedBlocks = (N + 63) / 64;

    // layer 1: h1 = relu((A_hat @ feat) @ W1 + b1)      (fp16 out)
    k_agg_gemm<<<fusedBlocks, 256, 0, stream>>>(feat_h, row_start, edges, W1t, b1,
                                                nullptr, nullptr, h1_h, N);
    // layer 2: H = h1 + relu((A_hat @ h1) @ W2 + b2)    (fp32 out)
    k_agg_gemm<<<fusedBlocks, 256, 0, stream>>>(h1_h, row_start, edges, W2t, b2,
                                                h1_h, H, nullptr, N);
    // pool + final
    k_pool<<<B, 128, 0, stream>>>(H, target, size_subg, pooled, SZ);
    k_final<<<B, 128, 0, stream>>>(pooled, Wp, bp, (float*)d_out);
}

// Round 10
// 419.434 us; speedup vs baseline: 1.0490x; 1.0490x over previous
//
#include <hip/hip_runtime.h>

#define DD 128
#define CHUNK 2048      // edges per pass-1 block (782 blocks ~ 3/CU)
#define BSH 8           // bucket = dst >> 8  (256 nodes/bucket)
#define MAXBK 512       // max coarse buckets (N <= 131072)

typedef _Float16 half8 __attribute__((ext_vector_type(8)));
typedef _Float16 half4v __attribute__((ext_vector_type(4)));
typedef float floatx4 __attribute__((ext_vector_type(4)));

// ---------------- bucket-level histogram (LDS-aggregated) ----------------
__global__ __launch_bounds__(256) void k_bhist(const int* __restrict__ dst,
                                               int* __restrict__ bcounts, int E, int NB) {
    __shared__ int lh[MAXBK];
    int tid = threadIdx.x;
    for (int b = tid; b < MAXBK; b += 256) lh[b] = 0;
    __syncthreads();
    int stride = gridDim.x * 256;
    for (int k = blockIdx.x * 256 + tid; k < E; k += stride)
        atomicAdd(&lh[dst[k] >> BSH], 1);
    __syncthreads();
    for (int b = tid; b < NB; b += 256) {
        int c = lh[b];
        if (c) atomicAdd(&bcounts[b], c);
    }
}

// ---------------- bucket scan: bucket_start, row_start[N], zero gcur ----------------
__global__ __launch_bounds__(512) void k_bscan(const int* __restrict__ bcounts,
                                               int* __restrict__ bucket_start,
                                               int* __restrict__ gcur,
                                               int* __restrict__ row_start_N,
                                               int NB, int E) {
    __shared__ int s[512];
    int t = threadIdx.x;
    int v = (t < NB) ? bcounts[t] : 0;
    s[t] = v;
    __syncthreads();
    for (int off = 1; off < 512; off <<= 1) {
        int x = (t >= off) ? s[t - off] : 0;
        __syncthreads();
        s[t] += x;
        __syncthreads();
    }
    if (t < NB) bucket_start[t] = s[t] - v;           // exclusive
    if (t == NB - 1) bucket_start[NB] = s[t];         // == E
    if (t == 0) *row_start_N = E;
    gcur[t] = 0;
}

// ---------------- pass 1: bucket-bin edges, direct global run-writes ----------------
// rec = { src | dlocal<<17 , w_bits }   (requires N <= 2^17, dlocal < 256)
__global__ __launch_bounds__(256) void k_pass1(const int* __restrict__ src,
                                               const int* __restrict__ dst,
                                               const float* __restrict__ w,
                                               const int* __restrict__ bucket_start,
                                               int* __restrict__ gcur,
                                               int2* __restrict__ out, int E, int NB) {
    __shared__ int lhist[MAXBK];
    __shared__ int lbase[MAXBK];
    __shared__ int lcur[MAXBK];
    int tid = threadIdx.x;
    int beg = blockIdx.x * CHUNK;
    int end = min(beg + CHUNK, E);

    for (int b = tid; b < MAXBK; b += 256) { lhist[b] = 0; lcur[b] = 0; }
    __syncthreads();
    for (int k = beg + tid; k < end; k += 256)
        atomicAdd(&lhist[dst[k] >> BSH], 1);
    __syncthreads();
    for (int b = tid; b < NB; b += 256) {
        int c = lhist[b];
        if (c) lbase[b] = bucket_start[b] + atomicAdd(&gcur[b], c);
    }
    __syncthreads();
    for (int k = beg + tid; k < end; k += 256) {
        int d = dst[k];
        int b = d >> BSH;
        int loc = atomicAdd(&lcur[b], 1);
        out[lbase[b] + loc] =
            make_int2(src[k] | ((d & ((1 << BSH) - 1)) << 17), __float_as_int(w[k]));
    }
}

// ---------------- pass 2: per-bucket count+scan+place, all LDS-local ----------------
__global__ __launch_bounds__(512) void k_pass2(const int2* __restrict__ bkt,
                                               const int* __restrict__ bucket_start,
                                               int* __restrict__ row_start,
                                               int2* __restrict__ edges, int N) {
    __shared__ int lhist[1 << BSH];
    __shared__ int loff[1 << BSH];
    __shared__ int lcur[1 << BSH];
    int tid = threadIdx.x;
    int b = blockIdx.x;
    int d0 = b << BSH;
    int sb = bucket_start[b], se = bucket_start[b + 1];

    if (tid < (1 << BSH)) lhist[tid] = 0;
    __syncthreads();
    for (int i = sb + tid; i < se; i += 512)
        atomicAdd(&lhist[(unsigned)bkt[i].x >> 17], 1);
    __syncthreads();
    if (tid < 64) {
        int base = tid * 4, v[4], s = 0;
        #pragma unroll
        for (int j = 0; j < 4; ++j) { v[j] = lhist[base + j]; s += v[j]; }
        int sc = s;
        #pragma unroll
        for (int off = 1; off < 64; off <<= 1) {
            int t = __shfl_up(sc, off, 64);
            if (tid >= off) sc += t;
        }
        int excl = sc - s;
        #pragma unroll
        for (int j = 0; j < 4; ++j) {
            loff[base + j] = excl; lcur[base + j] = excl; excl += v[j];
        }
    }
    __syncthreads();
    if (tid < (1 << BSH)) {
        int d = d0 + tid;
        if (d < N) row_start[d] = sb + loff[tid];
    }
    for (int i = sb + tid; i < se; i += 512) {
        int2 r = bkt[i];
        int dl = (unsigned)r.x >> 17;
        int p = sb + atomicAdd(&lcur[dl], 1);
        edges[p] = make_int2(r.x & 0x1FFFF, r.y);
    }
}

// ---------------- merged casts: feat f32->f16 + W1/W2 transpose-cast ----------------
__global__ void k_cast_all(const float* __restrict__ feat, _Float16* __restrict__ feat_h,
                           const float* __restrict__ W1, _Float16* __restrict__ W1t,
                           const float* __restrict__ W2, _Float16* __restrict__ W2t,
                           int n4, int n4Blocks) {
    int blk = blockIdx.x;
    if (blk < n4Blocks) {
        int i = blk * 256 + threadIdx.x;
        if (i >= n4) return;
        float4 v = reinterpret_cast<const float4*>(feat)[i];
        half4v h;
        h.x = (_Float16)v.x; h.y = (_Float16)v.y; h.z = (_Float16)v.z; h.w = (_Float16)v.w;
        reinterpret_cast<half4v*>(feat_h)[i] = h;
    } else {
        int idx = (blk - n4Blocks) * 256 + threadIdx.x;   // 0..32767
        const float* W = (idx < DD * DD) ? W1 : W2;
        _Float16* Wt = (idx < DD * DD) ? W1t : W2t;
        int id = idx & (DD * DD - 1);
        int n = id >> 7, k = id & 127;
        Wt[n * DD + k] = (_Float16)W[k * DD + n];
    }
}

// ---------------- aggregation: one wave per dst; 16 lanes/row, 4 rows per gather ----
__global__ __launch_bounds__(256) void k_aggregate_h(const _Float16* __restrict__ x,
                                                     const int* __restrict__ row_start,
                                                     const int2* __restrict__ edges,
                                                     _Float16* __restrict__ out, int N) {
    int wid = (blockIdx.x * blockDim.x + threadIdx.x) >> 6;
    int lane = threadIdx.x & 63;
    if (wid >= N) return;
    int g = lane >> 4;    // edge group 0..3
    int sl = lane & 15;   // 16B chunk: cols sl*8 .. sl*8+7
    int beg = row_start[wid], end = row_start[wid + 1];
    float acc[8] = {0.f, 0.f, 0.f, 0.f, 0.f, 0.f, 0.f, 0.f};
    int i = beg;
    for (; i + 16 <= end; i += 16) {
        int2 e[4];
        #pragma unroll
        for (int u = 0; u < 4; ++u) e[u] = edges[i + u * 4 + g];
        half8 v[4];
        #pragma unroll
        for (int u = 0; u < 4; ++u)
            v[u] = *reinterpret_cast<const half8*>(x + (size_t)e[u].x * DD + sl * 8);
        #pragma unroll
        for (int u = 0; u < 4; ++u) {
            float wv = __int_as_float(e[u].y);
            #pragma unroll
            for (int j = 0; j < 8; ++j)
                acc[j] = fmaf((float)v[u][j], wv, acc[j]);
        }
    }
    for (; i < end; i += 4) {
        int rem = end - i;                 // >= 1
        int2 e = edges[i + min(g, rem - 1)];
        half8 v = *reinterpret_cast<const half8*>(x + (size_t)e.x * DD + sl * 8);
        float wv = (g < rem) ? __int_as_float(e.y) : 0.f;
        #pragma unroll
        for (int j = 0; j < 8; ++j)
            acc[j] = fmaf((float)v[j], wv, acc[j]);
    }
    #pragma unroll
    for (int j = 0; j < 8; ++j) {
        acc[j] += __shfl_xor(acc[j], 16, 64);
        acc[j] += __shfl_xor(acc[j], 32, 64);
    }
    if (g == 0) {
        half8 o;
        #pragma unroll
        for (int j = 0; j < 8; ++j) o[j] = (_Float16)acc[j];
        *reinterpret_cast<half8*>(out + (size_t)wid * DD + sl * 8) = o;
    }
}

// ---------------- MFMA GEMM (operand-swapped): out = relu(A @ W + b) [+ resid] ----
// mfma(Wt_frag, A_frag, acc): D col(lane&15) = A-row m, D row(q*4+r) = W out-col.
// => thread holds out[row0 + t*16 + m][c*16 + q*4 .. +3]  -> contiguous epilogue.
__global__ __launch_bounds__(256) void k_gemm_mfma(const _Float16* __restrict__ A,
                                                   const _Float16* __restrict__ Wt,
                                                   const float* __restrict__ bias,
                                                   const _Float16* __restrict__ resid_h,
                                                   _Float16* __restrict__ out_f16,
                                                   int nrows) {
    int wave = threadIdx.x >> 6;
    int lane = threadIdx.x & 63;
    int row0 = blockIdx.x * 128 + wave * 32;
    int m = lane & 15;
    int q = lane >> 4;

    floatx4 acc[2][8];
    #pragma unroll
    for (int t = 0; t < 2; ++t)
        #pragma unroll
        for (int c = 0; c < 8; ++c)
            acc[t][c] = (floatx4){0.f, 0.f, 0.f, 0.f};

    #pragma unroll
    for (int ks = 0; ks < 4; ++ks) {
        int kbase = ks * 32 + q * 8;
        half8 a0 = *reinterpret_cast<const half8*>(A + (size_t)(row0 + m) * DD + kbase);
        half8 a1 = *reinterpret_cast<const half8*>(A + (size_t)(row0 + 16 + m) * DD + kbase);
        #pragma unroll
        for (int c = 0; c < 8; ++c) {
            half8 b = *reinterpret_cast<const half8*>(Wt + (size_t)(c * 16 + m) * DD + kbase);
            acc[0][c] = __builtin_amdgcn_mfma_f32_16x16x32_f16(b, a0, acc[0][c], 0, 0, 0);
            acc[1][c] = __builtin_amdgcn_mfma_f32_16x16x32_f16(b, a1, acc[1][c], 0, 0, 0);
        }
    }

    #pragma unroll
    for (int t = 0; t < 2; ++t) {
        int row = row0 + t * 16 + m;
        if (row >= nrows) continue;
        size_t rb = (size_t)row * DD;
        #pragma unroll
        for (int c = 0; c < 8; ++c) {
            int col = c * 16 + q * 4;
            float4 bv = *reinterpret_cast<const float4*>(&bias[col]);
            float o[4] = {acc[t][c][0] + bv.x, acc[t][c][1] + bv.y,
                          acc[t][c][2] + bv.z, acc[t][c][3] + bv.w};
            #pragma unroll
            for (int r = 0; r < 4; ++r) o[r] = o[r] > 0.f ? o[r] : 0.f;
            if (resid_h) {
                half4v r4 = *reinterpret_cast<const half4v*>(&resid_h[rb + col]);
                #pragma unroll
                for (int r = 0; r < 4; ++r) o[r] += (float)r4[r];
            }
            half4v h;
            #pragma unroll
            for (int r = 0; r < 4; ++r) h[r] = (_Float16)o[r];
            *reinterpret_cast<half4v*>(&out_f16[rb + col]) = h;
        }
    }
}

// ---------------- fused: mean pool + target residual + relu(@Wp+bp) + L2 norm ----
__global__ __launch_bounds__(128) void k_pool_final(const _Float16* __restrict__ h,
                                                    const int* __restrict__ target,
                                                    const float* __restrict__ size_subg,
                                                    const float* __restrict__ Wp,
                                                    const float* __restrict__ bp,
                                                    float* __restrict__ out, int SZ) {
    __shared__ float p[DD];
    __shared__ float wsum[2];
    int b = blockIdx.x;
    int c = threadIdx.x;
    const _Float16* hp = h + (size_t)b * SZ * DD;
    float s = 0.f;
    for (int n = 0; n < SZ; ++n) s += (float)hp[(size_t)n * DD + c];
    int t = target[b];
    p[c] = s / size_subg[b] + (float)h[(size_t)t * DD + c];
    __syncthreads();
    float acc = 0.f;
    #pragma unroll 4
    for (int k = 0; k < DD; ++k) acc = fmaf(p[k], Wp[k * DD + c], acc);
    float e = acc + bp[c];
    e = e > 0.f ? e : 0.f;
    float sq = e * e;
    #pragma unroll
    for (int off = 32; off > 0; off >>= 1) sq += __shfl_down(sq, off, 64);
    int lane = c & 63, w = c >> 6;
    if (lane == 0) wsum[w] = sq;
    __syncthreads();
    float norm = sqrtf(wsum[0] + wsum[1]);
    float scale = 1.f / fmaxf(norm, 1e-12f);
    out[b * DD + c] = e * scale;
}

extern "C" void kernel_launch(void* const* d_in, const int* in_sizes, int n_in,
                              void* d_out, int out_size, void* d_ws, size_t ws_size,
                              hipStream_t stream) {
    const float* feat      = (const float*)d_in[0];
    const float* edge_w    = (const float*)d_in[1];
    const float* W1        = (const float*)d_in[2];
    const float* b1        = (const float*)d_in[3];
    const float* W2        = (const float*)d_in[4];
    const float* b2        = (const float*)d_in[5];
    const float* Wp        = (const float*)d_in[6];
    const float* bp        = (const float*)d_in[7];
    const float* size_subg = (const float*)d_in[8];
    const int*   edge_src  = (const int*)d_in[9];
    const int*   edge_dst  = (const int*)d_in[10];
    const int*   target    = (const int*)d_in[12];

    const int N  = in_sizes[0] / DD;
    const int E  = in_sizes[1];
    const int B  = in_sizes[8];
    const int SZ = N / B;

    const int gemmBlocks = (N + 127) / 128;
    const int P = gemmBlocks * 128;               // padded rows for gemm A-loads
    const int NB = (N + (1 << BSH) - 1) >> BSH;   // coarse buckets (<= MAXBK)

    char* ws = (char*)d_ws;
    size_t off = 0;
    auto alloc = [&](size_t bytes) {
        void* p = ws + off;
        off += (bytes + 255) & ~(size_t)255;
        return p;
    };
    // bufA: feat_h, later agg2 output.  bufB: agg1 output, later H (fp16).
    _Float16* bufA   = (_Float16*)alloc((size_t)P * DD * 2);
    _Float16* bufB   = (_Float16*)alloc((size_t)P * DD * 2);
    _Float16* h1_h   = (_Float16*)alloc((size_t)P * DD * 2);
    _Float16* W1t    = (_Float16*)alloc((size_t)DD * DD * 2);
    _Float16* W2t    = (_Float16*)alloc((size_t)DD * DD * 2);
    int*   row_start = (int*)alloc(((size_t)N + 1) * 4);
    int*   bcounts      = (int*)alloc((size_t)MAXBK * 4);
    int*   bucket_start = (int*)alloc(((size_t)MAXBK + 1) * 4);
    int*   gcur         = (int*)alloc((size_t)MAXBK * 4);
    int2*  edges_bkt = (int2*)alloc((size_t)E * 8);
    int2*  edges     = (int2*)alloc((size_t)E * 8);

    // ---- CSR build: bucket hist -> bucket scan -> pass1 -> pass2 ----
    hipMemsetAsync(bcounts, 0, (size_t)MAXBK * 4, stream);
    k_bhist<<<512, 256, 0, stream>>>(edge_dst, bcounts, E, NB);
    k_bscan<<<1, 512, 0, stream>>>(bcounts, bucket_start, gcur, row_start + N, NB, E);
    int p1Blocks = (E + CHUNK - 1) / CHUNK;
    k_pass1<<<p1Blocks, 256, 0, stream>>>(edge_src, edge_dst, edge_w, bucket_start,
                                          gcur, edges_bkt, E, NB);
    k_pass2<<<NB, 512, 0, stream>>>(edges_bkt, bucket_start, row_start, edges, N);

    // ---- merged casts ----
    int n4 = N * DD / 4;
    int n4Blocks = (n4 + 255) / 256;
    k_cast_all<<<n4Blocks + 2 * DD * DD / 256, 256, 0, stream>>>(
        feat, bufA, W1, W1t, W2, W2t, n4, n4Blocks);

    int aggBlocks = (N * 64 + 255) / 256;   // one wave per node

    // layer 1: agg1 = A_hat @ feat (bufA -> bufB) ; h1 = relu(agg1 @ W1 + b1)
    k_aggregate_h<<<aggBlocks, 256, 0, stream>>>(bufA, row_start, edges, bufB, N);
    k_gemm_mfma<<<gemmBlocks, 256, 0, stream>>>(bufB, W1t, b1, nullptr, h1_h, N);
    // layer 2: agg2 = A_hat @ h1 (h1_h -> bufA) ; H = h1 + relu(agg2 @ W2 + b2) (fp16, bufB)
    k_aggregate_h<<<aggBlocks, 256, 0, stream>>>(h1_h, row_start, edges, bufA, N);
    k_gemm_mfma<<<gemmBlocks, 256, 0, stream>>>(bufA, W2t, b2, h1_h, bufB, N);
    // fused pool + final
    k_pool_final<<<B, 128, 0, stream>>>(bufB, target, size_subg, Wp, bp,
                                        (float*)d_out, SZ);
}